// Round 1
// baseline (38673.224 us; speedup 1.0000x reference)
//
#include <hip/hip_runtime.h>
#include <math.h>

#define BB 128
#define TT 512
#define DD 512
#define HH 512
#define NN (BB*TT)   // 65536
#define PP 512
#define AA 32

// ---------------------------------------------------------------------------
// init: copy h0/c0 into workspace state
// ---------------------------------------------------------------------------
__global__ __launch_bounds__(256) void init_state(
    const float* __restrict__ h0_pi, const float* __restrict__ c0_pi,
    const float* __restrict__ h0_vf, const float* __restrict__ c0_vf,
    float* __restrict__ h2Pi, float* __restrict__ h2Vf,
    float* __restrict__ cPi, float* __restrict__ cVf)
{
    int i = blockIdx.x * blockDim.x + threadIdx.x;
    if (i < BB*HH) {
        h2Pi[i] = h0_pi[i];
        h2Vf[i] = h0_vf[i];
        cPi[i]  = c0_pi[i];
        cVf[i]  = c0_vf[i];
    }
}

// ---------------------------------------------------------------------------
// one LSTM time step for BOTH lstms.
// grid = 256 WGs: wg = grp*32 + s ; grp in [0,8) owns 16 envs; s in [0,32):
//   s<16  -> LSTM pi, hidden units [ (s&15)*32, +32 )
//   s>=16 -> LSTM vf, same unit range
// 256 threads: e = tid&15 (env), rg = tid>>4 (unit pair)
// LDS: xh[16][1024] floats (x | masked h), XOR-swizzled at float4 granularity.
// ---------------------------------------------------------------------------
__global__ __launch_bounds__(256) void lstm_step(
    const float* __restrict__ features, const float* __restrict__ starts,
    const float* __restrict__ Wih_pi, const float* __restrict__ Whh_pi,
    const float* __restrict__ bih_pi, const float* __restrict__ bhh_pi,
    const float* __restrict__ Wih_vf, const float* __restrict__ Whh_vf,
    const float* __restrict__ bih_vf, const float* __restrict__ bhh_vf,
    float* __restrict__ h2Pi, float* __restrict__ h2Vf,
    float* __restrict__ cPi, float* __restrict__ cVf,
    float* __restrict__ ysPi, float* __restrict__ ysVf,
    float* __restrict__ dout, int t)
{
    __shared__ float xh[16 * 1024];          // exactly 64 KB
    float4* xh4 = reinterpret_cast<float4*>(xh);

    const int wg   = blockIdx.x;
    const int grp  = wg >> 5;
    const int s    = wg & 31;
    const int isVf = (s >= 16);
    const int u0   = (s & 15) * 32;
    const int gbase = grp * 16;

    const float* Wih = isVf ? Wih_vf : Wih_pi;
    const float* Whh = isVf ? Whh_vf : Whh_pi;
    const float* bih = isVf ? bih_vf : bih_pi;
    const float* bhh = isVf ? bhh_vf : bhh_pi;
    float* h2  = isVf ? h2Vf : h2Pi;
    float* cst = isVf ? cVf  : cPi;
    float* ys  = isVf ? ysVf : ysPi;

    const int tid = threadIdx.x;
    const int p   = t & 1;
    const float* hprev = h2 + (size_t)p * (BB*HH);
    float*       hnext = h2 + (size_t)(1-p) * (BB*HH);

    // ---- stage x (slots [0,128) per env row, float4 units), swizzled
    #pragma unroll
    for (int i = 0; i < 8; ++i) {
        int f  = tid + i*256;        // 0..2047
        int e2 = f >> 7;             // env 0..15
        int kq = f & 127;
        int b  = gbase + e2;
        float4 v = reinterpret_cast<const float4*>(features + ((size_t)b*TT + t)*DD)[kq];
        xh4[e2*256 + (kq ^ e2)] = v;
    }
    // ---- stage masked h (slots [128,256))
    #pragma unroll
    for (int i = 0; i < 8; ++i) {
        int f  = tid + i*256;
        int e2 = f >> 7;
        int kq = f & 127;
        int b  = gbase + e2;
        float m = 1.0f - starts[(size_t)b*TT + t];
        float4 v = reinterpret_cast<const float4*>(hprev + (size_t)b*HH)[kq];
        v.x *= m; v.y *= m; v.z *= m; v.w *= m;
        xh4[e2*256 + 128 + (kq ^ e2)] = v;
    }
    __syncthreads();

    const int e  = tid & 15;
    const int rg = tid >> 4;           // 0..15
    const int b  = gbase + e;
    const int u1 = u0 + rg*2;

    float acc[2][4];
    #pragma unroll
    for (int j = 0; j < 2; ++j)
        #pragma unroll
        for (int q = 0; q < 4; ++q) acc[j][q] = 0.0f;

    const float4* xrow = xh4 + e*256;

    // ---- x part : Wih rows (q*H + u) , K = 512
    {
        const float* wb[2][4];
        #pragma unroll
        for (int j = 0; j < 2; ++j)
            #pragma unroll
            for (int q = 0; q < 4; ++q)
                wb[j][q] = Wih + ((size_t)(q*HH + u1 + j)) * DD;
        #pragma unroll 2
        for (int kq = 0; kq < 128; ++kq) {
            float4 xv = xrow[kq ^ e];
            #pragma unroll
            for (int j = 0; j < 2; ++j)
                #pragma unroll
                for (int q = 0; q < 4; ++q) {
                    float4 wv = reinterpret_cast<const float4*>(wb[j][q])[kq];
                    acc[j][q] += wv.x*xv.x + wv.y*xv.y + wv.z*xv.z + wv.w*xv.w;
                }
        }
    }
    // ---- h part : Whh rows , K = 512
    {
        const float* wb[2][4];
        #pragma unroll
        for (int j = 0; j < 2; ++j)
            #pragma unroll
            for (int q = 0; q < 4; ++q)
                wb[j][q] = Whh + ((size_t)(q*HH + u1 + j)) * HH;
        #pragma unroll 2
        for (int kq = 0; kq < 128; ++kq) {
            float4 hv = xrow[128 + (kq ^ e)];
            #pragma unroll
            for (int j = 0; j < 2; ++j)
                #pragma unroll
                for (int q = 0; q < 4; ++q) {
                    float4 wv = reinterpret_cast<const float4*>(wb[j][q])[kq];
                    acc[j][q] += wv.x*hv.x + wv.y*hv.y + wv.z*hv.z + wv.w*hv.w;
                }
        }
    }

    // ---- gates -> state update (gate order i,f,g,o)
    const float m = 1.0f - starts[(size_t)b*TT + t];
    #pragma unroll
    for (int j = 0; j < 2; ++j) {
        const int u = u1 + j;
        float gi = acc[j][0] + bih[u]        + bhh[u];
        float gf = acc[j][1] + bih[HH+u]     + bhh[HH+u];
        float gc = acc[j][2] + bih[2*HH+u]   + bhh[2*HH+u];
        float go = acc[j][3] + bih[3*HH+u]   + bhh[3*HH+u];
        float ii = 1.0f / (1.0f + expf(-gi));
        float ff = 1.0f / (1.0f + expf(-gf));
        float gg = tanhf(gc);
        float oo = 1.0f / (1.0f + expf(-go));
        float cprev = cst[(size_t)b*HH + u] * m;
        float cn = ff * cprev + ii * gg;
        float hn = oo * tanhf(cn);
        cst[(size_t)b*HH + u]   = cn;
        hnext[(size_t)b*HH + u] = hn;
        ys[((size_t)b*TT + t)*HH + u] = hn;
        if (t == TT-1) {
            dout[(size_t)(isVf ? 5 : 3)*NN + (size_t)b*HH + u] = hn;
            dout[(size_t)(isVf ? 6 : 4)*NN + (size_t)b*HH + u] = cn;
        }
    }
}

// ---------------------------------------------------------------------------
// fused MLP (2 layers) + head. One WG = 16 rows. 256 threads.
// LDS: smem[16384] floats = 64 KB: xs (8192) | hid (8192, aliased by red).
// All tiles stored XOR-swizzled at float4 granularity: slot4(r,kq).
// ---------------------------------------------------------------------------
__device__ __forceinline__ int slot4(int r, int kq) { return r*128 + (kq ^ (r & 7)); }

__global__ __launch_bounds__(256) void mlp_head(
    const float* __restrict__ ysBuf,
    const float* __restrict__ w1, const float* __restrict__ b1,
    const float* __restrict__ w2, const float* __restrict__ b2,
    const float* __restrict__ hw, const float* __restrict__ hb,
    float* __restrict__ dout, int isPi)
{
    __shared__ float smem[16384];
    float4* xs4  = reinterpret_cast<float4*>(smem);          // slots [0,2048)
    float4* hid4 = xs4 + 2048;                               // slots [0,2048)
    float*  red  = smem + 8192;                              // aliases hid

    const int tid = threadIdx.x;
    const size_t row0 = (size_t)blockIdx.x * 16;

    // ---- stage 16 rows of ys
    #pragma unroll
    for (int i = 0; i < 8; ++i) {
        int f = tid + i*256;
        int r = f >> 7, kq = f & 127;
        float4 v = reinterpret_cast<const float4*>(ysBuf + (row0 + r)*HH)[kq];
        xs4[slot4(r, kq)] = v;
    }
    __syncthreads();

    const int cq = tid & 127;          // column quad: cols cq*4..+3
    const int r0 = (tid >> 7) * 8;     // 0 or 8

    // ---- layer 1: hid = relu(xs @ w1^T + b1)
    {
        float acc[8][4];
        #pragma unroll
        for (int r = 0; r < 8; ++r)
            #pragma unroll
            for (int c = 0; c < 4; ++c) acc[r][c] = 0.0f;
        const float* wr0 = w1 + (size_t)(cq*4 + 0)*HH;
        const float* wr1 = w1 + (size_t)(cq*4 + 1)*HH;
        const float* wr2 = w1 + (size_t)(cq*4 + 2)*HH;
        const float* wr3 = w1 + (size_t)(cq*4 + 3)*HH;
        for (int kq2 = 0; kq2 < 128; ++kq2) {
            float4 wa = reinterpret_cast<const float4*>(wr0)[kq2];
            float4 wbv= reinterpret_cast<const float4*>(wr1)[kq2];
            float4 wc = reinterpret_cast<const float4*>(wr2)[kq2];
            float4 wd = reinterpret_cast<const float4*>(wr3)[kq2];
            #pragma unroll
            for (int r = 0; r < 8; ++r) {
                float4 xv = xs4[slot4(r0 + r, kq2)];
                acc[r][0] += wa.x*xv.x + wa.y*xv.y + wa.z*xv.z + wa.w*xv.w;
                acc[r][1] += wbv.x*xv.x + wbv.y*xv.y + wbv.z*xv.z + wbv.w*xv.w;
                acc[r][2] += wc.x*xv.x + wc.y*xv.y + wc.z*xv.z + wc.w*xv.w;
                acc[r][3] += wd.x*xv.x + wd.y*xv.y + wd.z*xv.z + wd.w*xv.w;
            }
        }
        #pragma unroll
        for (int r = 0; r < 8; ++r) {
            float4 o;
            o.x = fmaxf(acc[r][0] + b1[cq*4+0], 0.0f);
            o.y = fmaxf(acc[r][1] + b1[cq*4+1], 0.0f);
            o.z = fmaxf(acc[r][2] + b1[cq*4+2], 0.0f);
            o.w = fmaxf(acc[r][3] + b1[cq*4+3], 0.0f);
            hid4[slot4(r0 + r, cq)] = o;
        }
    }
    __syncthreads();

    // ---- layer 2: lat = hid @ w2^T + b2  -> back into xs
    {
        float acc[8][4];
        #pragma unroll
        for (int r = 0; r < 8; ++r)
            #pragma unroll
            for (int c = 0; c < 4; ++c) acc[r][c] = 0.0f;
        const float* wr0 = w2 + (size_t)(cq*4 + 0)*HH;
        const float* wr1 = w2 + (size_t)(cq*4 + 1)*HH;
        const float* wr2 = w2 + (size_t)(cq*4 + 2)*HH;
        const float* wr3 = w2 + (size_t)(cq*4 + 3)*HH;
        for (int kq2 = 0; kq2 < 128; ++kq2) {
            float4 wa = reinterpret_cast<const float4*>(wr0)[kq2];
            float4 wbv= reinterpret_cast<const float4*>(wr1)[kq2];
            float4 wc = reinterpret_cast<const float4*>(wr2)[kq2];
            float4 wd = reinterpret_cast<const float4*>(wr3)[kq2];
            #pragma unroll
            for (int r = 0; r < 8; ++r) {
                float4 xv = hid4[slot4(r0 + r, kq2)];
                acc[r][0] += wa.x*xv.x + wa.y*xv.y + wa.z*xv.z + wa.w*xv.w;
                acc[r][1] += wbv.x*xv.x + wbv.y*xv.y + wbv.z*xv.z + wbv.w*xv.w;
                acc[r][2] += wc.x*xv.x + wc.y*xv.y + wc.z*xv.z + wc.w*xv.w;
                acc[r][3] += wd.x*xv.x + wd.y*xv.y + wd.z*xv.z + wd.w*xv.w;
            }
        }
        __syncthreads();   // everyone done reading hid before xs overwrite? (hid!=xs, but keep phases clean)
        #pragma unroll
        for (int r = 0; r < 8; ++r) {
            float4 o;
            o.x = acc[r][0] + b2[cq*4+0];
            o.y = acc[r][1] + b2[cq*4+1];
            o.z = acc[r][2] + b2[cq*4+2];
            o.w = acc[r][3] + b2[cq*4+3];
            xs4[slot4(r0 + r, cq)] = o;
        }
    }
    __syncthreads();

    // ---- heads (lat lives in xs, swizzled; red aliases hid region)
    if (isPi) {
        const int r = tid & 15;
        const int a = tid >> 4;        // 0..15 -> actions a and a+16
        float acc0 = 0.0f, acc1 = 0.0f;
        for (int k = 0; k < PP; ++k) {
            float lv = smem[slot4(r, k >> 2)*4 + (k & 3)];
            acc0 += lv * hw[(size_t)a*PP + k];
            acc1 += lv * hw[(size_t)(a+16)*PP + k];
        }
        red[r*33 + a]      = acc0 + hb[a];
        red[r*33 + a + 16] = acc1 + hb[a+16];
        __syncthreads();
        if (tid < 16) {
            float mx = -INFINITY; int am = 0;
            #pragma unroll
            for (int a2 = 0; a2 < AA; ++a2) {
                float v = red[tid*33 + a2];
                if (v > mx) { mx = v; am = a2; }
            }
            float se = 0.0f;
            #pragma unroll
            for (int a2 = 0; a2 < AA; ++a2) se += expf(red[tid*33 + a2] - mx);
            size_t n = row0 + tid;
            dout[n] = (float)am;                     // actions
            dout[(size_t)2*NN + n] = -logf(se);      // log_prob of argmax
        }
    } else {
        const int r  = tid & 15;
        const int ch = tid >> 4;       // 16 chunks of 32
        float acc = 0.0f;
        for (int k = ch*32; k < ch*32 + 32; ++k)
            acc += smem[slot4(r, k >> 2)*4 + (k & 3)] * hw[k];
        red[r*33 + ch] = acc;
        __syncthreads();
        if (tid < 16) {
            float v = hb[0];
            #pragma unroll
            for (int c2 = 0; c2 < 16; ++c2) v += red[tid*33 + c2];
            dout[(size_t)NN + row0 + tid] = v;       // values
        }
    }
}

// ---------------------------------------------------------------------------
extern "C" void kernel_launch(void* const* d_in, const int* in_sizes, int n_in,
                              void* d_out, int out_size, void* d_ws, size_t ws_size,
                              hipStream_t stream) {
    const float* features = (const float*)d_in[0];
    const float* starts   = (const float*)d_in[1];
    const float* h0_pi = (const float*)d_in[2];
    const float* c0_pi = (const float*)d_in[3];
    const float* h0_vf = (const float*)d_in[4];
    const float* c0_vf = (const float*)d_in[5];
    const float* Wih_pi = (const float*)d_in[6];
    const float* Whh_pi = (const float*)d_in[7];
    const float* bih_pi = (const float*)d_in[8];
    const float* bhh_pi = (const float*)d_in[9];
    const float* Wih_vf = (const float*)d_in[10];
    const float* Whh_vf = (const float*)d_in[11];
    const float* bih_vf = (const float*)d_in[12];
    const float* bhh_vf = (const float*)d_in[13];
    const float* pol_w1 = (const float*)d_in[14];
    const float* pol_b1 = (const float*)d_in[15];
    const float* pol_w2 = (const float*)d_in[16];
    const float* pol_b2 = (const float*)d_in[17];
    const float* val_w1 = (const float*)d_in[18];
    const float* val_b1 = (const float*)d_in[19];
    const float* val_w2 = (const float*)d_in[20];
    const float* val_b2 = (const float*)d_in[21];
    const float* actor_w  = (const float*)d_in[22];
    const float* actor_b  = (const float*)d_in[23];
    const float* critic_w = (const float*)d_in[24];
    const float* critic_b = (const float*)d_in[25];
    float* out = (float*)d_out;

    float* ws   = (float*)d_ws;
    float* ysPi = ws;                                   // N*H
    float* ysVf = ysPi + (size_t)NN*HH;                 // N*H
    float* h2Pi = ysVf + (size_t)NN*HH;                 // 2*B*H
    float* h2Vf = h2Pi + 2*(size_t)BB*HH;               // 2*B*H
    float* cPi  = h2Vf + 2*(size_t)BB*HH;               // B*H
    float* cVf  = cPi  + (size_t)BB*HH;                 // B*H

    hipLaunchKernelGGL(init_state, dim3(256), dim3(256), 0, stream,
                       h0_pi, c0_pi, h0_vf, c0_vf, h2Pi, h2Vf, cPi, cVf);

    for (int t = 0; t < TT; ++t) {
        hipLaunchKernelGGL(lstm_step, dim3(256), dim3(256), 0, stream,
                           features, starts,
                           Wih_pi, Whh_pi, bih_pi, bhh_pi,
                           Wih_vf, Whh_vf, bih_vf, bhh_vf,
                           h2Pi, h2Vf, cPi, cVf, ysPi, ysVf, out, t);
    }

    hipLaunchKernelGGL(mlp_head, dim3(4096), dim3(256), 0, stream,
                       ysPi, pol_w1, pol_b1, pol_w2, pol_b2, actor_w, actor_b, out, 1);
    hipLaunchKernelGGL(mlp_head, dim3(4096), dim3(256), 0, stream,
                       ysVf, val_w1, val_b1, val_w2, val_b2, critic_w, critic_b, out, 0);
}

// Round 2
// 11008.495 us; speedup vs baseline: 3.5130x; 3.5130x over previous
//
#include <hip/hip_runtime.h>
#include <math.h>

#define BB 128
#define TT 512
#define DD 512
#define HH 512
#define NN (BB*TT)   // 65536
#define PP 512
#define AA 32

typedef unsigned short u16;
typedef unsigned int   u32;
typedef __attribute__((ext_vector_type(8))) short short8;
typedef __attribute__((ext_vector_type(4))) float f32x4;

__device__ __forceinline__ u16 f2bf(float f){
    u32 x = __float_as_uint(f);
    u32 r = (x + 0x7fffu + ((x >> 16) & 1u)) >> 16;   // RNE
    return (u16)r;
}
__device__ __forceinline__ float bf2f(u16 u){
    return __uint_as_float(((u32)u) << 16);
}
__device__ __forceinline__ f32x4 mfma16(short8 a, short8 b, f32x4 c){
    return __builtin_amdgcn_mfma_f32_16x16x32_bf16(a, b, c, 0, 0, 0);
}

// ---------------------------------------------------------------------------
// prep: permute+split LSTM weights. col c = u*4+g  <-  src row g*512+u.
// ---------------------------------------------------------------------------
__global__ __launch_bounds__(256) void prep_lstm_w(
    const float* __restrict__ Wih_pi, const float* __restrict__ Whh_pi,
    const float* __restrict__ bih_pi, const float* __restrict__ bhh_pi,
    const float* __restrict__ Wih_vf, const float* __restrict__ Whh_vf,
    const float* __restrict__ bih_vf, const float* __restrict__ bhh_vf,
    u16* __restrict__ wihHi, u16* __restrict__ wihLo,
    u16* __restrict__ whhHi, u16* __restrict__ whhLo,
    float* __restrict__ biasP)
{
    long i = (long)blockIdx.x*256 + threadIdx.x;
    if (i >= 2L*2048*512) return;
    int L = (int)(i >> 20);
    int rem = (int)(i & 1048575);
    int c = rem >> 9, k = rem & 511;
    int u = c >> 2, g = c & 3;
    long src = (long)(g*512 + u)*512 + k;
    float wih = (L ? Wih_vf : Wih_pi)[src];
    float whh = (L ? Whh_vf : Whh_pi)[src];
    u16 h1 = f2bf(wih); wihHi[i] = h1; wihLo[i] = f2bf(wih - bf2f(h1));
    u16 h2 = f2bf(whh); whhHi[i] = h2; whhLo[i] = f2bf(whh - bf2f(h2));
    if (k == 0) {
        float b = (L ? bih_vf : bih_pi)[g*512+u] + (L ? bhh_vf : bhh_pi)[g*512+u];
        biasP[L*2048 + c] = b;
    }
}

// prep MLP weight planes: mat 0=w1pi 1=w1vf 2=w2pi 3=w2vf
__global__ __launch_bounds__(256) void prep_mlp_w(
    const float* __restrict__ w1pi, const float* __restrict__ w1vf,
    const float* __restrict__ w2pi, const float* __restrict__ w2vf,
    const float* __restrict__ b1pi, const float* __restrict__ b1vf,
    const float* __restrict__ b2pi, const float* __restrict__ b2vf,
    u16* __restrict__ mHi, u16* __restrict__ mLo, float* __restrict__ biasM)
{
    long i = (long)blockIdx.x*256 + threadIdx.x;
    if (i >= 4L*262144) return;
    int mat = (int)(i >> 18);
    int rem = (int)(i & 262143);
    const float* src = mat==0 ? w1pi : mat==1 ? w1vf : mat==2 ? w2pi : w2vf;
    float v = src[rem];
    u16 h = f2bf(v); mHi[i] = h; mLo[i] = f2bf(v - bf2f(h));
    if (rem < 512) {
        const float* bs = mat==0 ? b1pi : mat==1 ? b1vf : mat==2 ? b2pi : b2vf;
        biasM[mat*512 + rem] = bs[rem];
    }
}

// init h (pre-masked by starts[t=0]) + c
__global__ __launch_bounds__(256) void init_state_k(
    const float* __restrict__ h0_pi, const float* __restrict__ c0_pi,
    const float* __restrict__ h0_vf, const float* __restrict__ c0_vf,
    const float* __restrict__ starts,
    u16* __restrict__ hHi, u16* __restrict__ hLo, float* __restrict__ cSt)
{
    int i = blockIdx.x*256 + threadIdx.x;
    if (i >= 2*BB*HH) return;
    int L = i >> 16; int r = i & 65535;
    int e = r >> 9;
    float m = 1.0f - starts[(long)e*TT];
    float h = (L ? h0_vf : h0_pi)[r] * m;
    float c = (L ? c0_vf : c0_pi)[r] * m;
    long hidx = (long)L*131072 + r;    // [L][parity=0][e][u]
    u16 hh = f2bf(h);
    hHi[hidx] = hh; hLo[hidx] = f2bf(h - bf2f(hh));
    cSt[i] = c;
}

// ---------------------------------------------------------------------------
// generic K=512 split-bf16 GEMM, tile 128x128, 256 threads (4 waves, 64x64 each)
// AM: 0 = A fp32 (converted in staging, row mapping (m>>sh)*outer+(m&mask)+base)
//     1 = A hi/lo planes
// EM: 0 = +bias -> fp32 out   1 = +bias,relu -> planes   2 = +bias -> planes
// ---------------------------------------------------------------------------
template<int AM, int EM>
__global__ __launch_bounds__(256) void gemm_k512(
    const float* __restrict__ Afp,
    const u16* __restrict__ aHi, const u16* __restrict__ aLo, long aZ,
    int rowSh, int rowOuter, int rowBase,
    const u16* __restrict__ bHi, const u16* __restrict__ bLo, long bZ,
    const float* __restrict__ bias, long biasZ,
    float* __restrict__ outF, long outFZ, int outLd,
    u16* __restrict__ oHi, u16* __restrict__ oLo, long oZ)
{
    __shared__ u16 sAh[5120], sAl[5120], sBh[5120], sBl[5120];  // 128 x 40 each
    const int tid = threadIdx.x;
    const int z = blockIdx.z;
    const long Mbase = (long)blockIdx.x * 128;
    const long Nbase = (long)blockIdx.y * 128;
    const int r2 = tid >> 1, half = tid & 1;
    const long mstage = Mbase + r2;
    const long arow = (mstage >> rowSh) * (long)rowOuter + (mstage & (((long)1<<rowSh)-1)) + rowBase;
    const long brow = Nbase + r2;
    const int wid = tid >> 6, lane = tid & 63;
    const int mh = wid & 1, nh = wid >> 1;
    const int l15 = lane & 15, quad = lane >> 4;

    f32x4 acc[4][4];
    #pragma unroll
    for (int i = 0; i < 4; ++i)
        #pragma unroll
        for (int j = 0; j < 4; ++j)
            acc[i][j] = (f32x4){0.f,0.f,0.f,0.f};

    const int sOffW = r2*40 + half*16;

    for (int kt = 0; kt < 16; ++kt) {
        const int k0 = kt*32;
        if constexpr (AM == 0) {
            const float* ap = Afp + arow*512 + k0 + half*16;
            float fv[16];
            #pragma unroll
            for (int q = 0; q < 4; ++q) *(float4*)(fv + q*4) = ((const float4*)ap)[q];
            short8 vh0, vh1, vl0, vl1;
            #pragma unroll
            for (int i = 0; i < 8; ++i){
                u16 h  = f2bf(fv[i]);   vh0[i] = (short)h;  vl0[i] = (short)f2bf(fv[i]   - bf2f(h));
                u16 h2 = f2bf(fv[8+i]); vh1[i] = (short)h2; vl1[i] = (short)f2bf(fv[8+i] - bf2f(h2));
            }
            *(short8*)(sAh + sOffW) = vh0; *(short8*)(sAh + sOffW + 8) = vh1;
            *(short8*)(sAl + sOffW) = vl0; *(short8*)(sAl + sOffW + 8) = vl1;
        } else {
            const u16* ph = aHi + (long)z*aZ + arow*512 + k0 + half*16;
            const u16* pl = aLo + (long)z*aZ + arow*512 + k0 + half*16;
            *(short8*)(sAh + sOffW) = *(const short8*)ph;
            *(short8*)(sAh + sOffW + 8) = *(const short8*)(ph + 8);
            *(short8*)(sAl + sOffW) = *(const short8*)pl;
            *(short8*)(sAl + sOffW + 8) = *(const short8*)(pl + 8);
        }
        {
            const u16* ph = bHi + (long)z*bZ + brow*512 + k0 + half*16;
            const u16* pl = bLo + (long)z*bZ + brow*512 + k0 + half*16;
            *(short8*)(sBh + sOffW) = *(const short8*)ph;
            *(short8*)(sBh + sOffW + 8) = *(const short8*)(ph + 8);
            *(short8*)(sBl + sOffW) = *(const short8*)pl;
            *(short8*)(sBl + sOffW + 8) = *(const short8*)(pl + 8);
        }
        __syncthreads();
        short8 bh[4], bl[4];
        #pragma unroll
        for (int nt = 0; nt < 4; ++nt){
            int bo = (nh*64 + nt*16 + l15)*40 + quad*8;
            bh[nt] = *(const short8*)(sBh + bo);
            bl[nt] = *(const short8*)(sBl + bo);
        }
        #pragma unroll
        for (int mt = 0; mt < 4; ++mt){
            int ao = (mh*64 + mt*16 + l15)*40 + quad*8;
            short8 ah = *(const short8*)(sAh + ao);
            short8 al = *(const short8*)(sAl + ao);
            #pragma unroll
            for (int nt = 0; nt < 4; ++nt){
                acc[mt][nt] = mfma16(ah, bh[nt], acc[mt][nt]);
                acc[mt][nt] = mfma16(ah, bl[nt], acc[mt][nt]);
                acc[mt][nt] = mfma16(al, bh[nt], acc[mt][nt]);
            }
        }
        __syncthreads();
    }
    #pragma unroll
    for (int nt = 0; nt < 4; ++nt){
        const long col = Nbase + nh*64 + nt*16 + l15;
        const float bv = bias[(long)z*biasZ + col];
        #pragma unroll
        for (int mt = 0; mt < 4; ++mt){
            const long rowm = Mbase + mh*64 + mt*16 + quad*4;
            #pragma unroll
            for (int rr = 0; rr < 4; ++rr){
                float v = acc[mt][nt][rr] + bv;
                const long m = rowm + rr;
                if constexpr (EM == 0) {
                    outF[(long)z*outFZ + m*(long)outLd + col] = v;
                } else {
                    if constexpr (EM == 1) v = fmaxf(v, 0.f);
                    u16 h = f2bf(v);
                    u16 l = f2bf(v - bf2f(h));
                    oHi[(long)z*oZ + m*512 + col] = h;
                    oLo[(long)z*oZ + m*512 + col] = l;
                }
            }
        }
    }
}

// ---------------------------------------------------------------------------
// one LSTM step (both LSTMs): z = h_masked @ Whh'^T via split-bf16 MFMA, then
// gates from z + gx (gx = x@Wih'+bih+bhh precomputed). 256 WGs:
// bx = L*128 + mg*? : L=bx>>7, rb=bx&127, mg=rb&1 (64 envs), ng=rb>>1 (8 units)
// ---------------------------------------------------------------------------
__global__ __launch_bounds__(256) void lstm_step_mfma(
    u16* __restrict__ hHi, u16* __restrict__ hLo,      // [L][2][128][512]
    const u16* __restrict__ whhHi, const u16* __restrict__ whhLo,
    const float* __restrict__ gx, long gxLZ, int Csh, int tau,
    const float* __restrict__ starts,
    float* __restrict__ cSt,                            // [L][128][512] pre-masked
    u16* __restrict__ ysHi, u16* __restrict__ ysLo,     // [L][65536][512]
    float* __restrict__ dout, int t)
{
    __shared__ float zs[64*33];
    const int tid = threadIdx.x;
    const int bx = blockIdx.x;
    const int L = bx >> 7, rb = bx & 127, mg = rb & 1, ng = rb >> 1;
    const int wid = tid >> 6, lane = tid & 63, l15 = lane & 15, quad = lane >> 4;
    const int p = t & 1;

    const long aoff = ((long)((L*2+p)*128 + mg*64 + wid*16 + l15))*512 + quad*8;
    const u16* aHiP = hHi + aoff;
    const u16* aLoP = hLo + aoff;
    const long bo0 = ((long)(L*2048 + ng*32 + l15))*512 + quad*8;
    const u16* b0h = whhHi + bo0;          const u16* b0l = whhLo + bo0;
    const u16* b1h = whhHi + bo0 + 16*512; const u16* b1l = whhLo + bo0 + 16*512;

    f32x4 acc0 = {0.f,0.f,0.f,0.f}, acc1 = {0.f,0.f,0.f,0.f};
    #pragma unroll
    for (int kt = 0; kt < 16; ++kt){
        const int ko = kt*32;
        short8 ah = *(const short8*)(aHiP + ko);
        short8 al = *(const short8*)(aLoP + ko);
        short8 h0 = *(const short8*)(b0h + ko);
        short8 l0 = *(const short8*)(b0l + ko);
        short8 h1 = *(const short8*)(b1h + ko);
        short8 l1 = *(const short8*)(b1l + ko);
        acc0 = mfma16(ah, h0, acc0); acc0 = mfma16(ah, l0, acc0); acc0 = mfma16(al, h0, acc0);
        acc1 = mfma16(ah, h1, acc1); acc1 = mfma16(ah, l1, acc1); acc1 = mfma16(al, h1, acc1);
    }
    #pragma unroll
    for (int rr = 0; rr < 4; ++rr){
        int e = wid*16 + quad*4 + rr;
        zs[e*33 + l15]      = acc0[rr];
        zs[e*33 + 16 + l15] = acc1[rr];
    }
    __syncthreads();
    #pragma unroll
    for (int it = 0; it < 2; ++it){
        int f = tid + it*256;
        int e = f >> 3, j = f & 7;
        int Eg = mg*64 + e;
        int u = ng*8 + j;
        float zi = zs[e*33 + j*4+0];
        float zf = zs[e*33 + j*4+1];
        float zg = zs[e*33 + j*4+2];
        float zo = zs[e*33 + j*4+3];
        const float* gxr = gx + (long)L*gxLZ + ((long)((Eg<<Csh) + tau))*2048 + (ng*32 + j*4);
        float4 gv = *(const float4*)gxr;
        float gi_ = zi + gv.x, gf_ = zf + gv.y, gg_ = zg + gv.z, go_ = zo + gv.w;
        float ii = 1.f/(1.f+expf(-gi_));
        float ff = 1.f/(1.f+expf(-gf_));
        float gg = tanhf(gg_);
        float oo = 1.f/(1.f+expf(-go_));
        long cidx = (long)L*NN + (long)Eg*512 + u;
        float cold = cSt[cidx];
        float cn = ff*cold + ii*gg;
        float hn = oo * tanhf(cn);
        long yidx = ((long)L*NN + (long)Eg*TT + t)*512 + u;
        u16 yh = f2bf(hn);
        ysHi[yidx] = yh; ysLo[yidx] = f2bf(hn - bf2f(yh));
        float mn = 1.0f;
        if (t+1 < TT) mn = 1.0f - starts[(long)Eg*TT + (t+1)];
        cSt[cidx] = cn * mn;
        float hm = hn * mn;
        long hidx = ((long)((L*2 + (1-p))*128 + Eg))*512 + u;
        u16 hh = f2bf(hm);
        hHi[hidx] = hh; hLo[hidx] = f2bf(hm - bf2f(hh));
        if (t == TT-1) {
            dout[(long)(3+2*L)*NN + (long)Eg*512 + u] = hn;
            dout[(long)(4+2*L)*NN + (long)Eg*512 + u] = cn;
        }
    }
}

// ---------------------------------------------------------------------------
// heads: fp32 VALU (precision-critical argmax). 16 rows per WG for pi.
// ---------------------------------------------------------------------------
__global__ __launch_bounds__(256) void head_pi(
    const u16* __restrict__ latHi, const u16* __restrict__ latLo,
    const float* __restrict__ actor_w, const float* __restrict__ actor_b,
    float* __restrict__ dout, int rowBase)
{
    __shared__ float latS[16*516];
    __shared__ float lg[16*36];
    const int tid = threadIdx.x;
    const long r0 = (long)blockIdx.x * 16;
    {
        int rr = tid >> 4, seg = tid & 15;
        const u16* ph = latHi + (r0 + rr)*512 + seg*32;
        const u16* pl = latLo + (r0 + rr)*512 + seg*32;
        float* dst = latS + rr*516 + seg*32;
        #pragma unroll
        for (int ii = 0; ii < 4; ++ii){
            short8 vh = *(const short8*)(ph + ii*8);
            short8 vl = *(const short8*)(pl + ii*8);
            #pragma unroll
            for (int jj = 0; jj < 8; ++jj)
                dst[ii*8+jj] = bf2f((u16)vh[jj]) + bf2f((u16)vl[jj]);
        }
    }
    __syncthreads();
    {
        int rr = tid >> 4, a0 = (tid & 15)*2;
        const float4* lrow = (const float4*)(latS + rr*516);
        float acc0 = actor_b[a0], acc1 = actor_b[a0+1];
        for (int kq = 0; kq < 128; ++kq){
            float4 lv = lrow[kq];
            float4 w0 = ((const float4*)actor_w)[(a0  )*128 + kq];
            float4 w1 = ((const float4*)actor_w)[(a0+1)*128 + kq];
            acc0 += lv.x*w0.x + lv.y*w0.y + lv.z*w0.z + lv.w*w0.w;
            acc1 += lv.x*w1.x + lv.y*w1.y + lv.z*w1.z + lv.w*w1.w;
        }
        lg[rr*36 + a0]   = acc0;
        lg[rr*36 + a0+1] = acc1;
    }
    __syncthreads();
    if (tid < 16){
        float mx = -INFINITY; int am = 0;
        #pragma unroll
        for (int a = 0; a < AA; ++a){
            float v = lg[tid*36 + a];
            if (v > mx){ mx = v; am = a; }
        }
        float se = 0.f;
        #pragma unroll
        for (int a = 0; a < AA; ++a) se += expf(lg[tid*36 + a] - mx);
        long n = r0 + tid + rowBase;
        dout[n] = (float)am;
        dout[2L*NN + n] = -logf(se);
    }
}

__global__ __launch_bounds__(256) void head_vf(
    const u16* __restrict__ latHi, const u16* __restrict__ latLo,
    const float* __restrict__ critic_w, const float* __restrict__ critic_b,
    float* __restrict__ dout, int rowBase)
{
    __shared__ float part[256];
    const int tid = threadIdx.x;
    const long r0 = (long)blockIdx.x * 32;
    int rr = tid >> 3, seg = tid & 7;
    const u16* ph = latHi + (r0 + rr)*512 + seg*64;
    const u16* pl = latLo + (r0 + rr)*512 + seg*64;
    float acc = 0.f;
    #pragma unroll
    for (int ii = 0; ii < 8; ++ii){
        short8 vh = *(const short8*)(ph + ii*8);
        short8 vl = *(const short8*)(pl + ii*8);
        #pragma unroll
        for (int jj = 0; jj < 8; ++jj){
            float lv = bf2f((u16)vh[jj]) + bf2f((u16)vl[jj]);
            acc += lv * critic_w[seg*64 + ii*8 + jj];
        }
    }
    part[tid] = acc;
    __syncthreads();
    if (tid < 32){
        float v = critic_b[0];
        #pragma unroll
        for (int s = 0; s < 8; ++s) v += part[tid*8 + s];
        dout[(long)NN + r0 + rowBase + tid] = v;
    }
}

// ---------------------------------------------------------------------------
extern "C" void kernel_launch(void* const* d_in, const int* in_sizes, int n_in,
                              void* d_out, int out_size, void* d_ws, size_t ws_size,
                              hipStream_t stream) {
    const float* features = (const float*)d_in[0];
    const float* starts   = (const float*)d_in[1];
    const float* h0_pi = (const float*)d_in[2];
    const float* c0_pi = (const float*)d_in[3];
    const float* h0_vf = (const float*)d_in[4];
    const float* c0_vf = (const float*)d_in[5];
    const float* Wih_pi = (const float*)d_in[6];
    const float* Whh_pi = (const float*)d_in[7];
    const float* bih_pi = (const float*)d_in[8];
    const float* bhh_pi = (const float*)d_in[9];
    const float* Wih_vf = (const float*)d_in[10];
    const float* Whh_vf = (const float*)d_in[11];
    const float* bih_vf = (const float*)d_in[12];
    const float* bhh_vf = (const float*)d_in[13];
    const float* pol_w1 = (const float*)d_in[14];
    const float* pol_b1 = (const float*)d_in[15];
    const float* pol_w2 = (const float*)d_in[16];
    const float* pol_b2 = (const float*)d_in[17];
    const float* val_w1 = (const float*)d_in[18];
    const float* val_b1 = (const float*)d_in[19];
    const float* val_w2 = (const float*)d_in[20];
    const float* val_b2 = (const float*)d_in[21];
    const float* actor_w  = (const float*)d_in[22];
    const float* actor_b  = (const float*)d_in[23];
    const float* critic_w = (const float*)d_in[24];
    const float* critic_b = (const float*)d_in[25];
    float* out = (float*)d_out;

    size_t off = 0;
    auto alloc = [&](size_t b) {
        void* p = (char*)d_ws + off;
        off += (b + 255) & ~(size_t)255;
        return p;
    };
    u16* wihHi = (u16*)alloc(2L*2048*512*2);
    u16* wihLo = (u16*)alloc(2L*2048*512*2);
    u16* whhHi = (u16*)alloc(2L*2048*512*2);
    u16* whhLo = (u16*)alloc(2L*2048*512*2);
    float* biasP = (float*)alloc(2L*2048*4);
    u16* mHi = (u16*)alloc(4L*262144*2);
    u16* mLo = (u16*)alloc(4L*262144*2);
    float* biasM = (float*)alloc(4L*512*4);
    u16* hHi = (u16*)alloc(2L*2*128*512*2);
    u16* hLo = (u16*)alloc(2L*2*128*512*2);
    float* cSt = (float*)alloc(2L*128*512*4);
    u16* ysHi = (u16*)alloc(2L*NN*512*2);
    u16* ysLo = (u16*)alloc(2L*NN*512*2);
    size_t remain = (ws_size > off) ? (ws_size - off) : 0;

    // chunk sizes adaptive to workspace
    int C = 4;
    { const int cand[4] = {64,32,16,8};
      for (int i = 0; i < 4; ++i) if ((size_t)cand[i]*2097152 <= remain) { C = cand[i]; break; } }
    int R = 1024;
    { const int cand[4] = {16384,8192,4096,2048};
      for (int i = 0; i < 4; ++i) if ((size_t)cand[i]*8192 <= remain) { R = cand[i]; break; } }
    int Csh = __builtin_ctz(C);
    float* gxF   = (float*)((char*)d_ws + off);          // arena (fp32 gate-x)
    u16*  hidHi  = (u16*)((char*)d_ws + off);            // arena reused for MLP
    u16*  hidLo  = hidHi + 2L*R*512;
    u16*  latHi  = hidLo + 2L*R*512;
    u16*  latLo  = latHi + 2L*R*512;
    long  gxLZ   = (long)128*C*2048;

    prep_lstm_w<<<dim3((2097152+255)/256), dim3(256), 0, stream>>>(
        Wih_pi, Whh_pi, bih_pi, bhh_pi, Wih_vf, Whh_vf, bih_vf, bhh_vf,
        wihHi, wihLo, whhHi, whhLo, biasP);
    prep_mlp_w<<<dim3((1048576+255)/256), dim3(256), 0, stream>>>(
        pol_w1, val_w1, pol_w2, val_w2, pol_b1, val_b1, pol_b2, val_b2,
        mHi, mLo, biasM);
    init_state_k<<<dim3((131072+255)/256), dim3(256), 0, stream>>>(
        h0_pi, c0_pi, h0_vf, c0_vf, starts, hHi, hLo, cSt);

    for (int t0 = 0; t0 < TT; t0 += C) {
        gemm_k512<0,0><<<dim3(C,16,2), dim3(256), 0, stream>>>(
            features, nullptr, nullptr, 0L,
            Csh, TT, t0,
            wihHi, wihLo, 1048576L,
            biasP, 2048L,
            gxF, gxLZ, 2048,
            nullptr, nullptr, 0L);
        for (int t = t0; t < t0 + C; ++t) {
            lstm_step_mfma<<<dim3(256), dim3(256), 0, stream>>>(
                hHi, hLo, whhHi, whhLo,
                gxF, gxLZ, Csh, t - t0,
                starts, cSt, ysHi, ysLo, out, t);
        }
    }

    for (int rb = 0; rb < NN; rb += R) {
        gemm_k512<1,1><<<dim3(R/128,4,2), dim3(256), 0, stream>>>(
            nullptr, ysHi + (long)rb*512, ysLo + (long)rb*512, (long)NN*512,
            30, 0, 0,
            mHi, mLo, 262144L,
            biasM, 512L,
            nullptr, 0L, 0,
            hidHi, hidLo, (long)R*512);
        gemm_k512<1,2><<<dim3(R/128,4,2), dim3(256), 0, stream>>>(
            nullptr, hidHi, hidLo, (long)R*512,
            30, 0, 0,
            mHi + 2L*262144, mLo + 2L*262144, 262144L,
            biasM + 1024, 512L,
            nullptr, 0L, 0,
            latHi, latLo, (long)R*512);
        head_pi<<<dim3(R/16), dim3(256), 0, stream>>>(
            latHi, latLo, actor_w, actor_b, out, rb);
        head_vf<<<dim3(R/32), dim3(256), 0, stream>>>(
            latHi + (long)R*512, latLo + (long)R*512, critic_w, critic_b, out, rb);
    }
}